// Round 13
// baseline (802.541 us; speedup 1.0000x reference)
//
#include <hip/hip_runtime.h>

#define D 128
#define BN_EPS 1e-5f
#define SB 256   // scan blocks
#define ST 256   // scan threads

typedef short s16x8 __attribute__((ext_vector_type(8)));
typedef short s16x4 __attribute__((ext_vector_type(4)));
typedef float f32x4 __attribute__((ext_vector_type(4)));
typedef int   i32x2 __attribute__((ext_vector_type(2)));

// fp32 -> bf16 round-to-nearest-even
static __device__ __forceinline__ short f2bf(float f) {
    unsigned u = __builtin_bit_cast(unsigned, f);
    u += 0x7FFFu + ((u >> 16) & 1u);
    return (short)(u >> 16);
}
static __device__ __forceinline__ float bf2f(short s) {
    unsigned u = ((unsigned)(unsigned short)s) << 16;
    return __builtin_bit_cast(float, u);
}

// packed-fragment slot for W element (k, f)
static __device__ __forceinline__ int wslot(int k, int f) {
    int t = k >> 5, kg = (k >> 3) & 3, e = k & 7;
    int c = f >> 4, fl = f & 15;
    return (((t * 8 + c) * 64 + kg * 16 + fl) * 8) + e;
}

// ---------------- 0. cast x -> bf16 image ----------------------------------
__global__ __launch_bounds__(256) void k_xcast(
    const float* __restrict__ x, short* __restrict__ xb, int total8)
{
    int i = blockIdx.x * 256 + threadIdx.x;
    if (i >= total8) return;
    const float* p = x + (size_t)i * 8;
    f32x4 lo = __builtin_nontemporal_load((const f32x4*)p);
    f32x4 hi = __builtin_nontemporal_load((const f32x4*)(p + 4));
    s16x8 o;
    o[0] = f2bf(lo[0]); o[1] = f2bf(lo[1]); o[2] = f2bf(lo[2]); o[3] = f2bf(lo[3]);
    o[4] = f2bf(hi[0]); o[5] = f2bf(hi[1]); o[6] = f2bf(hi[2]); o[7] = f2bf(hi[3]);
    *(s16x8*)(xb + (size_t)i * 8) = o;
}

// ---------------- 1. histogram: deg[dst]++ --------------------------------
__global__ __launch_bounds__(256) void k_hist(
    const int* __restrict__ ei, int* __restrict__ deg, int E)
{
    int e = blockIdx.x * 256 + threadIdx.x;
    if (e >= E) return;
    atomicAdd(&deg[ei[E + e]], 1);
}

// ---------------- 2a. per-block partial sums -------------------------------
__global__ __launch_bounds__(ST) void k_scanA(
    const int* __restrict__ deg, int* __restrict__ bsum, int N, int chunk)
{
    int b = blockIdx.x;
    int start = b * chunk, end = min(start + chunk, N);
    int s = 0;
    for (int i = start + threadIdx.x; i < end; i += ST) s += deg[i];
    __shared__ int red[ST];
    red[threadIdx.x] = s;
    __syncthreads();
    for (int o = ST / 2; o > 0; o >>= 1) {
        if (threadIdx.x < o) red[threadIdx.x] += red[threadIdx.x + o];
        __syncthreads();
    }
    if (threadIdx.x == 0) bsum[b] = red[0];
}

// ---------------- 2b. per-block scan (absorbs block-sum scan; proven r11) --
__global__ __launch_bounds__(ST) void k_scanC(
    const int* __restrict__ deg, const int* __restrict__ bsum,
    int* __restrict__ offs, int* __restrict__ cur, int N, int chunk)
{
    int b = blockIdx.x;
    int start = b * chunk, end = min(start + chunk, N);
    __shared__ int btmp[SB];
    __shared__ int tmp[ST];
    __shared__ int carry;
    int t = threadIdx.x;
    btmp[t] = bsum[t];
    __syncthreads();
    for (int o = 1; o < SB; o <<= 1) {
        int u = (t >= o) ? btmp[t - o] : 0;
        __syncthreads();
        btmp[t] += u;
        __syncthreads();
    }
    if (t == 0) carry = (b == 0) ? 0 : btmp[b - 1];
    __syncthreads();
    for (int i0 = start; i0 < end; i0 += ST) {
        int i = i0 + t;
        int v = (i < end) ? deg[i] : 0;
        tmp[t] = v;
        __syncthreads();
        for (int o = 1; o < ST; o <<= 1) {
            int u = (t >= o) ? tmp[t - o] : 0;
            __syncthreads();
            tmp[t] += u;
            __syncthreads();
        }
        int incl = tmp[t];
        int total = tmp[ST - 1];
        if (i < end) {
            int ex = carry + incl - v;
            offs[i] = ex;
            cur[i] = ex;
        }
        __syncthreads();
        if (t == 0) carry += total;
        __syncthreads();
    }
}

// ---------------- 3. scatter (src, eid) into dst buckets -------------------
__global__ __launch_bounds__(256) void k_scatter(
    const int* __restrict__ ei, int* __restrict__ cur,
    int2* __restrict__ bucket, int E)
{
    int e = blockIdx.x * 256 + threadIdx.x;
    if (e >= E) return;
    int dst = ei[E + e];
    int pos = atomicAdd(&cur[dst], 1);
    bucket[pos] = make_int2(ei[e], e);
}

// ---------------- 4. aggregate: h[n] = bf16(x[n] + sum relu(x[src]+ea)) ----
// Round-10-proven shape: 4 nodes per wave, 16 lanes x 8 features per node;
// x gathered bf16 (L3-resident); ea/bucket NT; unroll x4.
__global__ __launch_bounds__(256) void k_aggr(
    const short* __restrict__ xb, const float* __restrict__ ea,
    const int2* __restrict__ bucket, const int* __restrict__ offs,
    const int* __restrict__ deg, short* __restrict__ h, int N)
{
    int node = blockIdx.x * 16 + (threadIdx.x >> 4);
    if (node >= N) return;
    int lane = threadIdx.x & 15;
    int c0 = lane * 8;
    int start = offs[node];
    int d = deg[node];
    const int2* bp = bucket + start;

    float acc[8];
    {
        s16x8 xs = *(const s16x8*)(xb + (size_t)node * D + c0);
        #pragma unroll
        for (int i = 0; i < 8; ++i) acc[i] = bf2f(xs[i]);
    }

    int e = 0;
    for (; e + 4 <= d; e += 4) {
        i32x2 b[4];
        #pragma unroll
        for (int j = 0; j < 4; ++j)
            b[j] = __builtin_nontemporal_load((const i32x2*)(bp + e + j));
        s16x8 xv[4];
        f32x4 a0[4], a1[4];
        #pragma unroll
        for (int j = 0; j < 4; ++j) {
            xv[j] = *(const s16x8*)(xb + (size_t)b[j][0] * D + c0);
            const float* ap = ea + (size_t)b[j][1] * D + c0;
            a0[j] = __builtin_nontemporal_load((const f32x4*)ap);
            a1[j] = __builtin_nontemporal_load((const f32x4*)(ap + 4));
        }
        #pragma unroll
        for (int j = 0; j < 4; ++j) {
            #pragma unroll
            for (int i = 0; i < 4; ++i) {
                acc[i]     += fmaxf(bf2f(xv[j][i])     + a0[j][i], 0.f);
                acc[i + 4] += fmaxf(bf2f(xv[j][i + 4]) + a1[j][i], 0.f);
            }
        }
    }
    for (; e < d; ++e) {
        i32x2 b = __builtin_nontemporal_load((const i32x2*)(bp + e));
        s16x8 xv = *(const s16x8*)(xb + (size_t)b[0] * D + c0);
        const float* ap = ea + (size_t)b[1] * D + c0;
        f32x4 a0 = __builtin_nontemporal_load((const f32x4*)ap);
        f32x4 a1 = __builtin_nontemporal_load((const f32x4*)(ap + 4));
        #pragma unroll
        for (int i = 0; i < 4; ++i) {
            acc[i]     += fmaxf(bf2f(xv[i])     + a0[i], 0.f);
            acc[i + 4] += fmaxf(bf2f(xv[i + 4]) + a1[i], 0.f);
        }
    }
    s16x8 o;
    #pragma unroll
    for (int i = 0; i < 8; ++i) o[i] = f2bf(acc[i]);
    *(s16x8*)(h + (size_t)node * D + c0) = o;
}

// ---------------- pack W1 (fp32 row-major) -> bf16 fragment image ----------
__global__ __launch_bounds__(256) void k_packW(
    const float* __restrict__ W, short* __restrict__ wp)
{
    int gid = blockIdx.x * 256 + threadIdx.x;   // 2048 threads; one 16B frag each
    int f = gid & 127;
    int kb = gid >> 7;
    s16x8 o;
    #pragma unroll
    for (int e = 0; e < 8; ++e)
        o[e] = f2bf(W[(kb * 8 + e) * D + f]);
    *(s16x8*)&wp[wslot(kb * 8, f)] = o;          // slots contiguous in e
}

// ---------------- MFMA GEMM: out = [relu](hin_bf16 @ W + bias) -------------
// Operand-swapped (proven r7). RELU=1 also accumulates BN stats (fused,
// proven r11/r12): per-lane partials -> shfl-reduce over 16 row-lanes -> atomics.
template<int RELU, int OBF>
__global__ __launch_bounds__(256) void k_mgemm(
    const short* __restrict__ hin, const short* __restrict__ wp,
    const float* __restrict__ bias, void* __restrict__ outp,
    float* __restrict__ gsum, float* __restrict__ gsq, int N)
{
    __shared__ __align__(16) short wB[D * D];   // 32KB packed frags
    int tid = threadIdx.x;
    #pragma unroll
    for (int i = 0; i < 8; ++i) {
        int q = i * 256 + tid;
        *(s16x8*)&wB[q * 8] = *(const s16x8*)&wp[q * 8];
    }
    __syncthreads();

    int wv = tid >> 6, l = tid & 63;
    int cl = l & 15, kg = l >> 4;
    int ntiles = (N + 15) >> 4;

    float4 bv[8];
    #pragma unroll
    for (int c = 0; c < 8; ++c) bv[c] = *(const float4*)&bias[c * 16 + kg * 4];

    f32x4 sc[8], sq[8];
    if (RELU) {
        #pragma unroll
        for (int c = 0; c < 8; ++c) { sc[c] = {0.f,0.f,0.f,0.f}; sq[c] = {0.f,0.f,0.f,0.f}; }
    }

    for (int tile = blockIdx.x * 4 + wv; tile < ntiles; tile += gridDim.x * 4) {
        int row0 = tile * 16;
        int rowA = min(row0 + cl, N - 1);
        const short* ap = hin + (size_t)rowA * D + kg * 8;
        s16x8 rF[4];
        #pragma unroll
        for (int t = 0; t < 4; ++t)
            rF[t] = *(const s16x8*)(ap + t * 32);

        bool ok = (row0 + cl < N);
        size_t obase = (size_t)(row0 + cl) * D + kg * 4;
        #pragma unroll
        for (int c = 0; c < 8; ++c) {
            f32x4 acc = { bv[c].x, bv[c].y, bv[c].z, bv[c].w };
            #pragma unroll
            for (int t = 0; t < 4; ++t) {
                s16x8 wF = *(const s16x8*)&wB[((t * 8 + c) * 64 + l) * 8];
                acc = __builtin_amdgcn_mfma_f32_16x16x32_bf16(wF, rF[t], acc, 0, 0, 0);
            }
            if (RELU) {
                acc[0] = fmaxf(acc[0], 0.f); acc[1] = fmaxf(acc[1], 0.f);
                acc[2] = fmaxf(acc[2], 0.f); acc[3] = fmaxf(acc[3], 0.f);
                if (ok) {
                    #pragma unroll
                    for (int r = 0; r < 4; ++r) {
                        sc[c][r] += acc[r];
                        sq[c][r] += acc[r] * acc[r];
                    }
                }
            }
            if (ok) {
                if (OBF) {
                    s16x4 o = { f2bf(acc[0]), f2bf(acc[1]), f2bf(acc[2]), f2bf(acc[3]) };
                    *(s16x4*)((short*)outp + obase + c * 16) = o;
                } else {
                    *(float4*)((float*)outp + obase + c * 16) =
                        make_float4(acc[0], acc[1], acc[2], acc[3]);
                }
            }
        }
    }

    if (RELU) {
        #pragma unroll
        for (int c = 0; c < 8; ++c) {
            #pragma unroll
            for (int r = 0; r < 4; ++r) {
                float s = sc[c][r], q = sq[c][r];
                s += __shfl_xor(s, 1); s += __shfl_xor(s, 2);
                s += __shfl_xor(s, 4); s += __shfl_xor(s, 8);
                q += __shfl_xor(q, 1); q += __shfl_xor(q, 2);
                q += __shfl_xor(q, 4); q += __shfl_xor(q, 8);
                if (cl == 0) {
                    atomicAdd(&gsum[c * 16 + kg * 4 + r], s);
                    atomicAdd(&gsq[c * 16 + kg * 4 + r], q);
                }
            }
        }
    }
}

// ---------------- fold BN into W2/b2; emit PACKED bf16 W2' + b2' -----------
__global__ __launch_bounds__(128) void k_fold(
    const float* __restrict__ gsum, const float* __restrict__ gsq,
    const float* __restrict__ gamma, const float* __restrict__ beta,
    const float* __restrict__ W2, const float* __restrict__ b2,
    short* __restrict__ wp2, float* __restrict__ b2p, int N)
{
    __shared__ float sS[D], tS[D];
    int j = threadIdx.x;
    float invN = 1.0f / (float)N;
    float mean = gsum[j] * invN;
    float var = gsq[j] * invN - mean * mean;
    float rstd = rsqrtf(var + BN_EPS);
    float s = rstd * gamma[j];
    sS[j] = s;
    tS[j] = beta[j] - mean * s;
    __syncthreads();
    float acc = b2[j];
    #pragma unroll 8
    for (int k = 0; k < D; ++k) {
        float w = W2[k * D + j];
        wp2[wslot(k, j)] = f2bf(sS[k] * w);
        acc = fmaf(tS[k], w, acc);
    }
    b2p[j] = acc;
}

extern "C" void kernel_launch(void* const* d_in, const int* in_sizes, int n_in,
                              void* d_out, int out_size, void* d_ws, size_t ws_size,
                              hipStream_t stream) {
    const float* x     = (const float*)d_in[0];
    const int*   ei    = (const int*)d_in[1];
    const float* ea    = (const float*)d_in[2];
    const float* W1    = (const float*)d_in[3];
    const float* b1    = (const float*)d_in[4];
    const float* gamma = (const float*)d_in[5];
    const float* beta  = (const float*)d_in[6];
    const float* W2    = (const float*)d_in[7];
    const float* b2    = (const float*)d_in[8];
    float* out = (float*)d_out;

    int N = in_sizes[0] / D;
    int E = in_sizes[1] / 2;

    // ---- workspace layout (memset region contiguous: deg|gsum|gsq) ----
    char* ws = (char*)d_ws;
    int2*  bucket = (int2*)ws;                             // E int2 (12.8 MB)
    int*   deg    = (int*)(ws + (size_t)E * sizeof(int2)); // N
    float* gsum   = (float*)(deg + N);                     // D
    float* gsq    = gsum + D;                              // D
    float* b2p    = gsq + D;                               // D
    int*   offs   = (int*)(b2p + D);                       // N
    int*   cur    = offs + N;                              // N
    int*   bsum   = cur + N;                               // SB
    short* wp1    = (short*)(bsum + SB);                   // D*D bf16
    short* wp2    = wp1 + D * D;                           // D*D bf16
    short* xb     = wp2 + D * D;                           // N*D bf16 (25.6 MB)
    short* h      = xb + (size_t)N * D;                    // N*D bf16
    short* h1     = h + (size_t)N * D;                     // N*D bf16

    // zero deg + gsum + gsq (contiguous; rest fully overwritten)
    hipMemsetAsync(deg, 0, (size_t)N * sizeof(int) + 2 * D * sizeof(float), stream);

    int chunk = (N + SB - 1) / SB;
    int eB = (E + 255) / 256;
    int x8 = (N * D) / 8;

    k_xcast<<<(x8 + 255) / 256, 256, 0, stream>>>(x, xb, x8);
    k_hist<<<eB, 256, 0, stream>>>(ei, deg, E);
    k_scanA<<<SB, ST, 0, stream>>>(deg, bsum, N, chunk);
    k_scanC<<<SB, ST, 0, stream>>>(deg, bsum, offs, cur, N, chunk);
    k_scatter<<<eB, 256, 0, stream>>>(ei, cur, bucket, E);
    k_aggr<<<(N + 15) / 16, 256, 0, stream>>>(xb, ea, bucket, offs, deg, h, N);

    int ntiles = (N + 15) / 16;
    int gB = (ntiles + 7) / 8;   // each wave: exactly 2 tiles
    k_packW<<<8, 256, 0, stream>>>(W1, wp1);
    k_mgemm<1, 1><<<gB, 256, 0, stream>>>(h, wp1, b1, h1, gsum, gsq, N);
    k_fold<<<1, 128, 0, stream>>>(gsum, gsq, gamma, beta, W2, b2, wp2, b2p, N);
    k_mgemm<0, 0><<<gB, 256, 0, stream>>>(h1, wp2, b2p, out, gsum, gsq, N);
}

// Round 14
// 516.328 us; speedup vs baseline: 1.5543x; 1.5543x over previous
//
#include <hip/hip_runtime.h>

#define D 128
#define BN_EPS 1e-5f
#define SB 256   // scan blocks
#define ST 256   // scan threads

typedef short s16x8 __attribute__((ext_vector_type(8)));
typedef short s16x4 __attribute__((ext_vector_type(4)));
typedef float f32x4 __attribute__((ext_vector_type(4)));
typedef int   i32x2 __attribute__((ext_vector_type(2)));

// fp32 -> bf16 round-to-nearest-even
static __device__ __forceinline__ short f2bf(float f) {
    unsigned u = __builtin_bit_cast(unsigned, f);
    u += 0x7FFFu + ((u >> 16) & 1u);
    return (short)(u >> 16);
}
static __device__ __forceinline__ float bf2f(short s) {
    unsigned u = ((unsigned)(unsigned short)s) << 16;
    return __builtin_bit_cast(float, u);
}

// packed-fragment slot for W element (k, f)
static __device__ __forceinline__ int wslot(int k, int f) {
    int t = k >> 5, kg = (k >> 3) & 3, e = k & 7;
    int c = f >> 4, fl = f & 15;
    return (((t * 8 + c) * 64 + kg * 16 + fl) * 8) + e;
}

// ---------------- 0. cast x -> bf16 image ----------------------------------
__global__ __launch_bounds__(256) void k_xcast(
    const float* __restrict__ x, short* __restrict__ xb, int total8)
{
    int i = blockIdx.x * 256 + threadIdx.x;
    if (i >= total8) return;
    const float* p = x + (size_t)i * 8;
    f32x4 lo = __builtin_nontemporal_load((const f32x4*)p);
    f32x4 hi = __builtin_nontemporal_load((const f32x4*)(p + 4));
    s16x8 o;
    o[0] = f2bf(lo[0]); o[1] = f2bf(lo[1]); o[2] = f2bf(lo[2]); o[3] = f2bf(lo[3]);
    o[4] = f2bf(hi[0]); o[5] = f2bf(hi[1]); o[6] = f2bf(hi[2]); o[7] = f2bf(hi[3]);
    *(s16x8*)(xb + (size_t)i * 8) = o;
}

// ---------------- 1. histogram: deg[dst]++ --------------------------------
__global__ __launch_bounds__(256) void k_hist(
    const int* __restrict__ ei, int* __restrict__ deg, int E)
{
    int e = blockIdx.x * 256 + threadIdx.x;
    if (e >= E) return;
    atomicAdd(&deg[ei[E + e]], 1);
}

// ---------------- 2a. per-block partial sums -------------------------------
__global__ __launch_bounds__(ST) void k_scanA(
    const int* __restrict__ deg, int* __restrict__ bsum, int N, int chunk)
{
    int b = blockIdx.x;
    int start = b * chunk, end = min(start + chunk, N);
    int s = 0;
    for (int i = start + threadIdx.x; i < end; i += ST) s += deg[i];
    __shared__ int red[ST];
    red[threadIdx.x] = s;
    __syncthreads();
    for (int o = ST / 2; o > 0; o >>= 1) {
        if (threadIdx.x < o) red[threadIdx.x] += red[threadIdx.x + o];
        __syncthreads();
    }
    if (threadIdx.x == 0) bsum[b] = red[0];
}

// ---------------- 2b. exclusive scan of block sums (1 block) ---------------
__global__ __launch_bounds__(SB) void k_scanB(int* __restrict__ bsum)
{
    __shared__ int tmp[SB];
    int t = threadIdx.x;
    int orig = bsum[t];
    tmp[t] = orig;
    __syncthreads();
    for (int o = 1; o < SB; o <<= 1) {
        int u = (t >= o) ? tmp[t - o] : 0;
        __syncthreads();
        tmp[t] += u;
        __syncthreads();
    }
    bsum[t] = tmp[t] - orig;   // exclusive
}

// ---------------- 2c. per-block scan with base → offsets + cursor ----------
__global__ __launch_bounds__(ST) void k_scanC(
    const int* __restrict__ deg, const int* __restrict__ bsum,
    int* __restrict__ offs, int* __restrict__ cur, int N, int chunk)
{
    int b = blockIdx.x;
    int start = b * chunk, end = min(start + chunk, N);
    __shared__ int tmp[ST];
    __shared__ int carry;
    int t = threadIdx.x;
    if (t == 0) carry = bsum[b];
    __syncthreads();
    for (int i0 = start; i0 < end; i0 += ST) {
        int i = i0 + t;
        int v = (i < end) ? deg[i] : 0;
        tmp[t] = v;
        __syncthreads();
        for (int o = 1; o < ST; o <<= 1) {
            int u = (t >= o) ? tmp[t - o] : 0;
            __syncthreads();
            tmp[t] += u;
            __syncthreads();
        }
        int incl = tmp[t];
        int total = tmp[ST - 1];
        if (i < end) {
            int ex = carry + incl - v;
            offs[i] = ex;
            cur[i] = ex;
        }
        __syncthreads();
        if (t == 0) carry += total;
        __syncthreads();
    }
}

// ---------------- 3. scatter (src, eid) into dst buckets -------------------
__global__ __launch_bounds__(256) void k_scatter(
    const int* __restrict__ ei, int* __restrict__ cur,
    int2* __restrict__ bucket, int E)
{
    int e = blockIdx.x * 256 + threadIdx.x;
    if (e >= E) return;
    int dst = ei[E + e];
    int pos = atomicAdd(&cur[dst], 1);
    bucket[pos] = make_int2(ei[e], e);
}

// ---------------- 4. aggregate: h[n] = bf16(x[n] + sum relu(x[src]+ea)) ----
// 4 nodes per 64-lane wave (16 lanes x 8 features each); x gathered as bf16
// (L3-resident 25.6MB); ea/bucket NT; unroll x4 -> 12 loads in flight/lane.
__global__ __launch_bounds__(256) void k_aggr(
    const short* __restrict__ xb, const float* __restrict__ ea,
    const int2* __restrict__ bucket, const int* __restrict__ offs,
    const int* __restrict__ deg, short* __restrict__ h, int N)
{
    int node = blockIdx.x * 16 + (threadIdx.x >> 4);
    if (node >= N) return;
    int lane = threadIdx.x & 15;
    int c0 = lane * 8;
    int start = offs[node];
    int d = deg[node];
    const int2* bp = bucket + start;

    float acc[8];
    {
        s16x8 xs = *(const s16x8*)(xb + (size_t)node * D + c0);
        #pragma unroll
        for (int i = 0; i < 8; ++i) acc[i] = bf2f(xs[i]);
    }

    int e = 0;
    for (; e + 4 <= d; e += 4) {
        i32x2 b[4];
        #pragma unroll
        for (int j = 0; j < 4; ++j)
            b[j] = __builtin_nontemporal_load((const i32x2*)(bp + e + j));
        s16x8 xv[4];
        f32x4 a0[4], a1[4];
        #pragma unroll
        for (int j = 0; j < 4; ++j) {
            xv[j] = *(const s16x8*)(xb + (size_t)b[j][0] * D + c0);
            const float* ap = ea + (size_t)b[j][1] * D + c0;
            a0[j] = __builtin_nontemporal_load((const f32x4*)ap);
            a1[j] = __builtin_nontemporal_load((const f32x4*)(ap + 4));
        }
        #pragma unroll
        for (int j = 0; j < 4; ++j) {
            #pragma unroll
            for (int i = 0; i < 4; ++i) {
                acc[i]     += fmaxf(bf2f(xv[j][i])     + a0[j][i], 0.f);
                acc[i + 4] += fmaxf(bf2f(xv[j][i + 4]) + a1[j][i], 0.f);
            }
        }
    }
    for (; e < d; ++e) {
        i32x2 b = __builtin_nontemporal_load((const i32x2*)(bp + e));
        s16x8 xv = *(const s16x8*)(xb + (size_t)b[0] * D + c0);
        const float* ap = ea + (size_t)b[1] * D + c0;
        f32x4 a0 = __builtin_nontemporal_load((const f32x4*)ap);
        f32x4 a1 = __builtin_nontemporal_load((const f32x4*)(ap + 4));
        #pragma unroll
        for (int i = 0; i < 4; ++i) {
            acc[i]     += fmaxf(bf2f(xv[i])     + a0[i], 0.f);
            acc[i + 4] += fmaxf(bf2f(xv[i + 4]) + a1[i], 0.f);
        }
    }
    s16x8 o;
    #pragma unroll
    for (int i = 0; i < 8; ++i) o[i] = f2bf(acc[i]);
    *(s16x8*)(h + (size_t)node * D + c0) = o;
}

// ---------------- pack W1 (fp32 row-major) -> bf16 fragment image ----------
__global__ __launch_bounds__(256) void k_packW(
    const float* __restrict__ W, short* __restrict__ wp)
{
    int gid = blockIdx.x * 256 + threadIdx.x;   // 2048 threads
    int f = gid & 127;
    int kb = gid >> 7;
    #pragma unroll
    for (int e = 0; e < 8; ++e) {
        int k = kb * 8 + e;
        wp[wslot(k, f)] = f2bf(W[k * D + f]);
    }
}

// ---------------- MFMA GEMM: out = [relu](hin_bf16 @ W + bias) -------------
// Operand-swapped (proven r7): D[f][r]; B-frag rows load DIRECTLY as s16x8.
// OBF=1: bf16 output (8B stores); OBF=0: fp32 output (16B stores).
template<int RELU, int OBF>
__global__ __launch_bounds__(256) void k_mgemm(
    const short* __restrict__ hin, const short* __restrict__ wp,
    const float* __restrict__ bias, void* __restrict__ outp, int N)
{
    __shared__ __align__(16) short wB[D * D];   // 32KB packed frags
    int tid = threadIdx.x;
    #pragma unroll
    for (int i = 0; i < 8; ++i) {
        int q = i * 256 + tid;
        *(s16x8*)&wB[q * 8] = *(const s16x8*)&wp[q * 8];
    }
    __syncthreads();

    int wv = tid >> 6, l = tid & 63;
    int cl = l & 15, kg = l >> 4;
    int ntiles = (N + 15) >> 4;

    float4 bv[8];
    #pragma unroll
    for (int c = 0; c < 8; ++c) bv[c] = *(const float4*)&bias[c * 16 + kg * 4];

    for (int tile = blockIdx.x * 4 + wv; tile < ntiles; tile += gridDim.x * 4) {
        int row0 = tile * 16;
        int rowA = min(row0 + cl, N - 1);
        const short* ap = hin + (size_t)rowA * D + kg * 8;
        s16x8 rF[4];
        #pragma unroll
        for (int t = 0; t < 4; ++t)
            rF[t] = *(const s16x8*)(ap + t * 32);

        bool ok = (row0 + cl < N);
        size_t obase = (size_t)(row0 + cl) * D + kg * 4;
        #pragma unroll
        for (int c = 0; c < 8; ++c) {
            f32x4 acc = { bv[c].x, bv[c].y, bv[c].z, bv[c].w };
            #pragma unroll
            for (int t = 0; t < 4; ++t) {
                s16x8 wF = *(const s16x8*)&wB[((t * 8 + c) * 64 + l) * 8];
                acc = __builtin_amdgcn_mfma_f32_16x16x32_bf16(wF, rF[t], acc, 0, 0, 0);
            }
            if (RELU) {
                acc[0] = fmaxf(acc[0], 0.f); acc[1] = fmaxf(acc[1], 0.f);
                acc[2] = fmaxf(acc[2], 0.f); acc[3] = fmaxf(acc[3], 0.f);
            }
            if (ok) {
                if (OBF) {
                    s16x4 o = { f2bf(acc[0]), f2bf(acc[1]), f2bf(acc[2]), f2bf(acc[3]) };
                    *(s16x4*)((short*)outp + obase + c * 16) = o;
                } else {
                    *(float4*)((float*)outp + obase + c * 16) =
                        make_float4(acc[0], acc[1], acc[2], acc[3]);
                }
            }
        }
    }
}

// ---------------- BN batch stats over bf16 h1 ------------------------------
__global__ __launch_bounds__(256) void k_stats(
    const short* __restrict__ h1, float* __restrict__ gsum,
    float* __restrict__ gsq, int N)
{
    __shared__ float ls[D], lq[D];
    int tid = threadIdx.x;
    if (tid < D) { ls[tid] = 0.f; lq[tid] = 0.f; }
    __syncthreads();
    int c0 = (tid & 15) * 8;
    float s[8], q[8];
    #pragma unroll
    for (int i = 0; i < 8; ++i) { s[i] = 0.f; q[i] = 0.f; }
    for (int r = blockIdx.x * 16 + (tid >> 4); r < N; r += gridDim.x * 16) {
        s16x8 v = *(const s16x8*)(h1 + (size_t)r * D + c0);
        #pragma unroll
        for (int i = 0; i < 8; ++i) {
            float f = bf2f(v[i]);
            s[i] += f; q[i] += f * f;
        }
    }
    #pragma unroll
    for (int i = 0; i < 8; ++i) {
        atomicAdd(&ls[c0 + i], s[i]);
        atomicAdd(&lq[c0 + i], q[i]);
    }
    __syncthreads();
    if (tid < D) {
        atomicAdd(&gsum[tid], ls[tid]);
        atomicAdd(&gsq[tid], lq[tid]);
    }
}

// ---------------- fold BN into W2/b2; emit PACKED bf16 W2' + b2' -----------
__global__ __launch_bounds__(128) void k_fold(
    const float* __restrict__ gsum, const float* __restrict__ gsq,
    const float* __restrict__ gamma, const float* __restrict__ beta,
    const float* __restrict__ W2, const float* __restrict__ b2,
    short* __restrict__ wp2, float* __restrict__ b2p, int N)
{
    __shared__ float sS[D], tS[D];
    int j = threadIdx.x;
    float invN = 1.0f / (float)N;
    float mean = gsum[j] * invN;
    float var = gsq[j] * invN - mean * mean;
    float rstd = rsqrtf(var + BN_EPS);
    float s = rstd * gamma[j];
    sS[j] = s;
    tS[j] = beta[j] - mean * s;
    __syncthreads();
    float acc = b2[j];
    #pragma unroll 4
    for (int k = 0; k < D; ++k) {
        float w = W2[k * D + j];
        wp2[wslot(k, j)] = f2bf(sS[k] * w);
        acc = fmaf(tS[k], w, acc);
    }
    b2p[j] = acc;
}

extern "C" void kernel_launch(void* const* d_in, const int* in_sizes, int n_in,
                              void* d_out, int out_size, void* d_ws, size_t ws_size,
                              hipStream_t stream) {
    const float* x     = (const float*)d_in[0];
    const int*   ei    = (const int*)d_in[1];
    const float* ea    = (const float*)d_in[2];
    const float* W1    = (const float*)d_in[3];
    const float* b1    = (const float*)d_in[4];
    const float* gamma = (const float*)d_in[5];
    const float* beta  = (const float*)d_in[6];
    const float* W2    = (const float*)d_in[7];
    const float* b2    = (const float*)d_in[8];
    float* out = (float*)d_out;

    int N = in_sizes[0] / D;
    int E = in_sizes[1] / 2;

    // ---- workspace layout (memset region contiguous: deg|gsum|gsq) ----
    char* ws = (char*)d_ws;
    int2*  bucket = (int2*)ws;                             // E int2 (12.8 MB)
    int*   deg    = (int*)(ws + (size_t)E * sizeof(int2)); // N
    float* gsum   = (float*)(deg + N);                     // D
    float* gsq    = gsum + D;                              // D
    float* b2p    = gsq + D;                               // D
    int*   offs   = (int*)(b2p + D);                       // N
    int*   cur    = offs + N;                              // N
    int*   bsum   = cur + N;                               // SB
    short* wp1    = (short*)(bsum + SB);                   // D*D bf16
    short* wp2    = wp1 + D * D;                           // D*D bf16
    short* xb     = wp2 + D * D;                           // N*D bf16 (25.6 MB)
    short* h      = xb + (size_t)N * D;                    // N*D bf16
    short* h1     = h + (size_t)N * D;                     // N*D bf16

    // zero deg + gsum + gsq (contiguous; rest fully overwritten)
    hipMemsetAsync(deg, 0, (size_t)N * sizeof(int) + 2 * D * sizeof(float), stream);

    int chunk = (N + SB - 1) / SB;
    int eB = (E + 255) / 256;
    int x8 = (N * D) / 8;

    k_xcast<<<(x8 + 255) / 256, 256, 0, stream>>>(x, xb, x8);
    k_hist<<<eB, 256, 0, stream>>>(ei, deg, E);
    k_scanA<<<SB, ST, 0, stream>>>(deg, bsum, N, chunk);
    k_scanB<<<1, SB, 0, stream>>>(bsum);
    k_scanC<<<SB, ST, 0, stream>>>(deg, bsum, offs, cur, N, chunk);
    k_scatter<<<eB, 256, 0, stream>>>(ei, cur, bucket, E);
    k_aggr<<<(N + 15) / 16, 256, 0, stream>>>(xb, ea, bucket, offs, deg, h, N);

    int ntiles = (N + 15) / 16;
    int gB = (ntiles + 7) / 8;   // each wave: exactly 2 tiles
    k_packW<<<8, 256, 0, stream>>>(W1, wp1);
    k_mgemm<1, 1><<<gB, 256, 0, stream>>>(h, wp1, b1, h1, N);
    k_stats<<<512, 256, 0, stream>>>(h1, gsum, gsq, N);
    k_fold<<<1, 128, 0, stream>>>(gsum, gsq, gamma, beta, W2, b2, wp2, b2p, N);
    k_mgemm<0, 0><<<gB, 256, 0, stream>>>(h1, wp2, b2p, out, N);
}

// Round 15
// 502.822 us; speedup vs baseline: 1.5961x; 1.0269x over previous
//
#include <hip/hip_runtime.h>

#define D 128
#define BN_EPS 1e-5f
#define SB 256   // scan blocks
#define ST 256   // scan threads

typedef short     s16x8 __attribute__((ext_vector_type(8)));
typedef short     s16x4 __attribute__((ext_vector_type(4)));
typedef float     f32x4 __attribute__((ext_vector_type(4)));
typedef _Float16  f16x8 __attribute__((ext_vector_type(8)));

// fp32 -> bf16 round-to-nearest-even
static __device__ __forceinline__ short f2bf(float f) {
    unsigned u = __builtin_bit_cast(unsigned, f);
    u += 0x7FFFu + ((u >> 16) & 1u);
    return (short)(u >> 16);
}
static __device__ __forceinline__ float bf2f(short s) {
    unsigned u = ((unsigned)(unsigned short)s) << 16;
    return __builtin_bit_cast(float, u);
}

// packed-fragment slot for W element (k, f)
static __device__ __forceinline__ int wslot(int k, int f) {
    int t = k >> 5, kg = (k >> 3) & 3, e = k & 7;
    int c = f >> 4, fl = f & 15;
    return (((t * 8 + c) * 64 + kg * 16 + fl) * 8) + e;
}

// ---------------- 0. cast x -> bf16 image ----------------------------------
__global__ __launch_bounds__(256) void k_xcast(
    const float* __restrict__ x, short* __restrict__ xb, int total8)
{
    int i = blockIdx.x * 256 + threadIdx.x;
    if (i >= total8) return;
    const float* p = x + (size_t)i * 8;
    f32x4 lo = __builtin_nontemporal_load((const f32x4*)p);
    f32x4 hi = __builtin_nontemporal_load((const f32x4*)(p + 4));
    s16x8 o;
    o[0] = f2bf(lo[0]); o[1] = f2bf(lo[1]); o[2] = f2bf(lo[2]); o[3] = f2bf(lo[3]);
    o[4] = f2bf(hi[0]); o[5] = f2bf(hi[1]); o[6] = f2bf(hi[2]); o[7] = f2bf(hi[3]);
    *(s16x8*)(xb + (size_t)i * 8) = o;
}

// ---------------- 1. histogram: deg[dst]++ --------------------------------
__global__ __launch_bounds__(256) void k_hist(
    const int* __restrict__ ei, int* __restrict__ deg, int E)
{
    int e = blockIdx.x * 256 + threadIdx.x;
    if (e >= E) return;
    atomicAdd(&deg[ei[E + e]], 1);
}

// ---------------- 2a. per-block partial sums -------------------------------
__global__ __launch_bounds__(ST) void k_scanA(
    const int* __restrict__ deg, int* __restrict__ bsum, int N, int chunk)
{
    int b = blockIdx.x;
    int start = b * chunk, end = min(start + chunk, N);
    int s = 0;
    for (int i = start + threadIdx.x; i < end; i += ST) s += deg[i];
    __shared__ int red[ST];
    red[threadIdx.x] = s;
    __syncthreads();
    for (int o = ST / 2; o > 0; o >>= 1) {
        if (threadIdx.x < o) red[threadIdx.x] += red[threadIdx.x + o];
        __syncthreads();
    }
    if (threadIdx.x == 0) bsum[b] = red[0];
}

// ---------------- 2b. exclusive scan of block sums (1 block) ---------------
__global__ __launch_bounds__(SB) void k_scanB(int* __restrict__ bsum)
{
    __shared__ int tmp[SB];
    int t = threadIdx.x;
    int orig = bsum[t];
    tmp[t] = orig;
    __syncthreads();
    for (int o = 1; o < SB; o <<= 1) {
        int u = (t >= o) ? tmp[t - o] : 0;
        __syncthreads();
        tmp[t] += u;
        __syncthreads();
    }
    bsum[t] = tmp[t] - orig;   // exclusive
}

// ---------------- 2c. per-block scan with base → offsets + cursor ----------
__global__ __launch_bounds__(ST) void k_scanC(
    const int* __restrict__ deg, const int* __restrict__ bsum,
    int* __restrict__ offs, int* __restrict__ cur, int N, int chunk)
{
    int b = blockIdx.x;
    int start = b * chunk, end = min(start + chunk, N);
    __shared__ int tmp[ST];
    __shared__ int carry;
    int t = threadIdx.x;
    if (t == 0) carry = bsum[b];
    __syncthreads();
    for (int i0 = start; i0 < end; i0 += ST) {
        int i = i0 + t;
        int v = (i < end) ? deg[i] : 0;
        tmp[t] = v;
        __syncthreads();
        for (int o = 1; o < ST; o <<= 1) {
            int u = (t >= o) ? tmp[t - o] : 0;
            __syncthreads();
            tmp[t] += u;
            __syncthreads();
        }
        int incl = tmp[t];
        int total = tmp[ST - 1];
        if (i < end) {
            int ex = carry + incl - v;
            offs[i] = ex;
            cur[i] = ex;
        }
        __syncthreads();
        if (t == 0) carry += total;
        __syncthreads();
    }
}

// ---------------- 3. build+scatter messages: mbuf[pos] = relu(x[src]+ea[e])
// Edge-parallel, 16 lanes/edge; ea read SEQUENTIAL; fp16 msg scattered to its
// CSR slot (256B granule, write-side). Proven correct r12.
__global__ __launch_bounds__(256) void k_msg(
    const short* __restrict__ xb, const float* __restrict__ ea,
    const int* __restrict__ ei, int* __restrict__ cur,
    _Float16* __restrict__ mbuf, int E)
{
    int e = blockIdx.x * 16 + (threadIdx.x >> 4);
    if (e >= E) return;
    int wtid = threadIdx.x & 63;
    int lane = threadIdx.x & 15;
    int c0 = lane * 8;
    int src = ei[e];
    int pos = 0;
    if (lane == 0) {
        int dst = ei[E + e];
        pos = atomicAdd(&cur[dst], 1);
    }
    pos = __shfl(pos, wtid & 48);   // broadcast from group's lane 0

    s16x8 xv = *(const s16x8*)(xb + (size_t)src * D + c0);
    const float* ap = ea + (size_t)e * D + c0;
    f32x4 a0 = __builtin_nontemporal_load((const f32x4*)ap);
    f32x4 a1 = __builtin_nontemporal_load((const f32x4*)(ap + 4));
    f16x8 m;
    #pragma unroll
    for (int i = 0; i < 4; ++i) {
        m[i]     = (_Float16)fmaxf(bf2f(xv[i])     + a0[i], 0.f);
        m[i + 4] = (_Float16)fmaxf(bf2f(xv[i + 4]) + a1[i], 0.f);
    }
    __builtin_nontemporal_store(m, (f16x8*)(mbuf + (size_t)pos * D + c0));
}

// ---------------- 4. aggregate: h[n] = bf16(x[n] + sum msg) ----------------
// Node-parallel, 16 lanes/node; node's messages CONTIGUOUS -> sequential read.
__global__ __launch_bounds__(256) void k_aggr2(
    const short* __restrict__ xb, const _Float16* __restrict__ mbuf,
    const int* __restrict__ offs, const int* __restrict__ deg,
    short* __restrict__ h, int N)
{
    int node = blockIdx.x * 16 + (threadIdx.x >> 4);
    if (node >= N) return;
    int lane = threadIdx.x & 15;
    int c0 = lane * 8;
    int start = offs[node];
    int d = deg[node];
    const _Float16* mp = mbuf + (size_t)start * D + c0;

    float acc[8];
    {
        s16x8 xs = *(const s16x8*)(xb + (size_t)node * D + c0);
        #pragma unroll
        for (int i = 0; i < 8; ++i) acc[i] = bf2f(xs[i]);
    }

    int e = 0;
    for (; e + 4 <= d; e += 4) {
        f16x8 m0 = __builtin_nontemporal_load((const f16x8*)(mp + (size_t)(e + 0) * D));
        f16x8 m1 = __builtin_nontemporal_load((const f16x8*)(mp + (size_t)(e + 1) * D));
        f16x8 m2 = __builtin_nontemporal_load((const f16x8*)(mp + (size_t)(e + 2) * D));
        f16x8 m3 = __builtin_nontemporal_load((const f16x8*)(mp + (size_t)(e + 3) * D));
        #pragma unroll
        for (int i = 0; i < 8; ++i)
            acc[i] += (float)m0[i] + (float)m1[i] + (float)m2[i] + (float)m3[i];
    }
    for (; e < d; ++e) {
        f16x8 m = __builtin_nontemporal_load((const f16x8*)(mp + (size_t)e * D));
        #pragma unroll
        for (int i = 0; i < 8; ++i) acc[i] += (float)m[i];
    }
    s16x8 o;
    #pragma unroll
    for (int i = 0; i < 8; ++i) o[i] = f2bf(acc[i]);
    *(s16x8*)(h + (size_t)node * D + c0) = o;
}

// ---------------- pack W1 (fp32 row-major) -> bf16 fragment image ----------
__global__ __launch_bounds__(256) void k_packW(
    const float* __restrict__ W, short* __restrict__ wp)
{
    int gid = blockIdx.x * 256 + threadIdx.x;   // 2048 threads
    int f = gid & 127;
    int kb = gid >> 7;
    #pragma unroll
    for (int e = 0; e < 8; ++e) {
        int k = kb * 8 + e;
        wp[wslot(k, f)] = f2bf(W[k * D + f]);
    }
}

// ---------------- MFMA GEMM: out = [relu](hin_bf16 @ W + bias) -------------
// Operand-swapped (proven r7); NO fused stats (r13/r14 A/B convicted them).
template<int RELU, int OBF>
__global__ __launch_bounds__(256) void k_mgemm(
    const short* __restrict__ hin, const short* __restrict__ wp,
    const float* __restrict__ bias, void* __restrict__ outp, int N)
{
    __shared__ __align__(16) short wB[D * D];   // 32KB packed frags
    int tid = threadIdx.x;
    #pragma unroll
    for (int i = 0; i < 8; ++i) {
        int q = i * 256 + tid;
        *(s16x8*)&wB[q * 8] = *(const s16x8*)&wp[q * 8];
    }
    __syncthreads();

    int wv = tid >> 6, l = tid & 63;
    int cl = l & 15, kg = l >> 4;
    int ntiles = (N + 15) >> 4;

    float4 bv[8];
    #pragma unroll
    for (int c = 0; c < 8; ++c) bv[c] = *(const float4*)&bias[c * 16 + kg * 4];

    for (int tile = blockIdx.x * 4 + wv; tile < ntiles; tile += gridDim.x * 4) {
        int row0 = tile * 16;
        int rowA = min(row0 + cl, N - 1);
        const short* ap = hin + (size_t)rowA * D + kg * 8;
        s16x8 rF[4];
        #pragma unroll
        for (int t = 0; t < 4; ++t)
            rF[t] = *(const s16x8*)(ap + t * 32);

        bool ok = (row0 + cl < N);
        size_t obase = (size_t)(row0 + cl) * D + kg * 4;
        #pragma unroll
        for (int c = 0; c < 8; ++c) {
            f32x4 acc = { bv[c].x, bv[c].y, bv[c].z, bv[c].w };
            #pragma unroll
            for (int t = 0; t < 4; ++t) {
                s16x8 wF = *(const s16x8*)&wB[((t * 8 + c) * 64 + l) * 8];
                acc = __builtin_amdgcn_mfma_f32_16x16x32_bf16(wF, rF[t], acc, 0, 0, 0);
            }
            if (RELU) {
                acc[0] = fmaxf(acc[0], 0.f); acc[1] = fmaxf(acc[1], 0.f);
                acc[2] = fmaxf(acc[2], 0.f); acc[3] = fmaxf(acc[3], 0.f);
            }
            if (ok) {
                if (OBF) {
                    s16x4 o = { f2bf(acc[0]), f2bf(acc[1]), f2bf(acc[2]), f2bf(acc[3]) };
                    *(s16x4*)((short*)outp + obase + c * 16) = o;
                } else {
                    *(float4*)((float*)outp + obase + c * 16) =
                        make_float4(acc[0], acc[1], acc[2], acc[3]);
                }
            }
        }
    }
}

// ---------------- BN batch stats over bf16 h1 ------------------------------
__global__ __launch_bounds__(256) void k_stats(
    const short* __restrict__ h1, float* __restrict__ gsum,
    float* __restrict__ gsq, int N)
{
    __shared__ float ls[D], lq[D];
    int tid = threadIdx.x;
    if (tid < D) { ls[tid] = 0.f; lq[tid] = 0.f; }
    __syncthreads();
    int c0 = (tid & 15) * 8;
    float s[8], q[8];
    #pragma unroll
    for (int i = 0; i < 8; ++i) { s[i] = 0.f; q[i] = 0.f; }
    for (int r = blockIdx.x * 16 + (tid >> 4); r < N; r += gridDim.x * 16) {
        s16x8 v = *(const s16x8*)(h1 + (size_t)r * D + c0);
        #pragma unroll
        for (int i = 0; i < 8; ++i) {
            float f = bf2f(v[i]);
            s[i] += f; q[i] += f * f;
        }
    }
    #pragma unroll
    for (int i = 0; i < 8; ++i) {
        atomicAdd(&ls[c0 + i], s[i]);
        atomicAdd(&lq[c0 + i], q[i]);
    }
    __syncthreads();
    if (tid < D) {
        atomicAdd(&gsum[tid], ls[tid]);
        atomicAdd(&gsq[tid], lq[tid]);
    }
}

// ---------------- fold BN into W2/b2; emit PACKED bf16 W2' + b2' -----------
__global__ __launch_bounds__(128) void k_fold(
    const float* __restrict__ gsum, const float* __restrict__ gsq,
    const float* __restrict__ gamma, const float* __restrict__ beta,
    const float* __restrict__ W2, const float* __restrict__ b2,
    short* __restrict__ wp2, float* __restrict__ b2p, int N)
{
    __shared__ float sS[D], tS[D];
    int j = threadIdx.x;
    float invN = 1.0f / (float)N;
    float mean = gsum[j] * invN;
    float var = gsq[j] * invN - mean * mean;
    float rstd = rsqrtf(var + BN_EPS);
    float s = rstd * gamma[j];
    sS[j] = s;
    tS[j] = beta[j] - mean * s;
    __syncthreads();
    float acc = b2[j];
    #pragma unroll 4
    for (int k = 0; k < D; ++k) {
        float w = W2[k * D + j];
        wp2[wslot(k, j)] = f2bf(sS[k] * w);
        acc = fmaf(tS[k], w, acc);
    }
    b2p[j] = acc;
}

extern "C" void kernel_launch(void* const* d_in, const int* in_sizes, int n_in,
                              void* d_out, int out_size, void* d_ws, size_t ws_size,
                              hipStream_t stream) {
    const float* x     = (const float*)d_in[0];
    const int*   ei    = (const int*)d_in[1];
    const float* ea    = (const float*)d_in[2];
    const float* W1    = (const float*)d_in[3];
    const float* b1    = (const float*)d_in[4];
    const float* gamma = (const float*)d_in[5];
    const float* beta  = (const float*)d_in[6];
    const float* W2    = (const float*)d_in[7];
    const float* b2    = (const float*)d_in[8];
    float* out = (float*)d_out;

    int N = in_sizes[0] / D;
    int E = in_sizes[1] / 2;

    // ---- workspace layout (mbuf first; memset region contiguous deg|gsum|gsq)
    char* ws = (char*)d_ws;
    _Float16* mbuf = (_Float16*)ws;                        // E*D fp16 (409.6 MB)
    int*   deg    = (int*)(ws + (size_t)E * D * sizeof(_Float16)); // N
    float* gsum   = (float*)(deg + N);                     // D
    float* gsq    = gsum + D;                              // D
    float* b2p    = gsq + D;                               // D
    int*   offs   = (int*)(b2p + D);                       // N
    int*   cur    = offs + N;                              // N
    int*   bsum   = cur + N;                               // SB
    short* wp1    = (short*)(bsum + SB);                   // D*D bf16
    short* wp2    = wp1 + D * D;                           // D*D bf16
    short* xb     = wp2 + D * D;                           // N*D bf16 (25.6 MB)
    short* h      = xb + (size_t)N * D;                    // N*D bf16
    short* h1     = h + (size_t)N * D;                     // N*D bf16

    // zero deg + gsum + gsq (contiguous; rest fully overwritten)
    hipMemsetAsync(deg, 0, (size_t)N * sizeof(int) + 2 * D * sizeof(float), stream);

    int chunk = (N + SB - 1) / SB;
    int eB = (E + 255) / 256;
    int x8 = (N * D) / 8;

    k_xcast<<<(x8 + 255) / 256, 256, 0, stream>>>(x, xb, x8);
    k_hist<<<eB, 256, 0, stream>>>(ei, deg, E);
    k_scanA<<<SB, ST, 0, stream>>>(deg, bsum, N, chunk);
    k_scanB<<<1, SB, 0, stream>>>(bsum);
    k_scanC<<<SB, ST, 0, stream>>>(deg, bsum, offs, cur, N, chunk);
    k_msg<<<(E + 15) / 16, 256, 0, stream>>>(xb, ea, ei, cur, mbuf, E);
    k_aggr2<<<(N + 15) / 16, 256, 0, stream>>>(xb, mbuf, offs, deg, h, N);

    int ntiles = (N + 15) / 16;
    int gB = (ntiles + 7) / 8;   // each wave: exactly 2 tiles
    k_packW<<<8, 256, 0, stream>>>(W1, wp1);
    k_mgemm<1, 1><<<gB, 256, 0, stream>>>(h, wp1, b1, h1, N);
    k_stats<<<512, 256, 0, stream>>>(h1, gsum, gsq, N);
    k_fold<<<1, 128, 0, stream>>>(gsum, gsq, gamma, beta, W2, b2, wp2, b2p, N);
    k_mgemm<0, 0><<<gB, 256, 0, stream>>>(h1, wp2, b2p, out, N);
}

// Round 16
// 488.814 us; speedup vs baseline: 1.6418x; 1.0287x over previous
//
#include <hip/hip_runtime.h>

#define D 128
#define BN_EPS 1e-5f
#define SB 256   // scan blocks
#define ST 256   // scan threads

typedef short     s16x8 __attribute__((ext_vector_type(8)));
typedef short     s16x4 __attribute__((ext_vector_type(4)));
typedef float     f32x4 __attribute__((ext_vector_type(4)));
typedef _Float16  f16x8 __attribute__((ext_vector_type(8)));

// fp32 -> bf16 round-to-nearest-even
static __device__ __forceinline__ short f2bf(float f) {
    unsigned u = __builtin_bit_cast(unsigned, f);
    u += 0x7FFFu + ((u >> 16) & 1u);
    return (short)(u >> 16);
}
static __device__ __forceinline__ float bf2f(short s) {
    unsigned u = ((unsigned)(unsigned short)s) << 16;
    return __builtin_bit_cast(float, u);
}

// packed-fragment slot for W element (k, f)
static __device__ __forceinline__ int wslot(int k, int f) {
    int t = k >> 5, kg = (k >> 3) & 3, e = k & 7;
    int c = f >> 4, fl = f & 15;
    return (((t * 8 + c) * 64 + kg * 16 + fl) * 8) + e;
}

// ---------------- 0. fused prep: xcast + hist + packW ----------------------
// total8 == E == 1.6M here; one grid covers both index spaces. First 2048
// threads additionally pack W1 (vectorized slot-store, proven r11/r12).
__global__ __launch_bounds__(256) void k_prep(
    const float* __restrict__ x, short* __restrict__ xb,
    const int* __restrict__ ei, int* __restrict__ deg,
    const float* __restrict__ W1, short* __restrict__ wp1,
    int total8, int E)
{
    int i = blockIdx.x * 256 + threadIdx.x;
    if (i < 2048) {                       // packW: 2048 threads x 16B frags
        int f = i & 127;
        int kb = i >> 7;
        s16x8 o;
        #pragma unroll
        for (int e = 0; e < 8; ++e)
            o[e] = f2bf(W1[(kb * 8 + e) * D + f]);
        *(s16x8*)&wp1[wslot(kb * 8, f)] = o;   // slots contiguous in e
    }
    if (i < total8) {                     // xcast
        const float* p = x + (size_t)i * 8;
        f32x4 lo = __builtin_nontemporal_load((const f32x4*)p);
        f32x4 hi = __builtin_nontemporal_load((const f32x4*)(p + 4));
        s16x8 o;
        o[0] = f2bf(lo[0]); o[1] = f2bf(lo[1]); o[2] = f2bf(lo[2]); o[3] = f2bf(lo[3]);
        o[4] = f2bf(hi[0]); o[5] = f2bf(hi[1]); o[6] = f2bf(hi[2]); o[7] = f2bf(hi[3]);
        *(s16x8*)(xb + (size_t)i * 8) = o;
    }
    if (i < E) {                          // hist
        atomicAdd(&deg[ei[E + i]], 1);
    }
}

// ---------------- 2a. per-block partial sums -------------------------------
__global__ __launch_bounds__(ST) void k_scanA(
    const int* __restrict__ deg, int* __restrict__ bsum, int N, int chunk)
{
    int b = blockIdx.x;
    int start = b * chunk, end = min(start + chunk, N);
    int s = 0;
    for (int i = start + threadIdx.x; i < end; i += ST) s += deg[i];
    __shared__ int red[ST];
    red[threadIdx.x] = s;
    __syncthreads();
    for (int o = ST / 2; o > 0; o >>= 1) {
        if (threadIdx.x < o) red[threadIdx.x] += red[threadIdx.x + o];
        __syncthreads();
    }
    if (threadIdx.x == 0) bsum[b] = red[0];
}

// ---------------- 2b. exclusive scan of block sums (1 block) ---------------
__global__ __launch_bounds__(SB) void k_scanB(int* __restrict__ bsum)
{
    __shared__ int tmp[SB];
    int t = threadIdx.x;
    int orig = bsum[t];
    tmp[t] = orig;
    __syncthreads();
    for (int o = 1; o < SB; o <<= 1) {
        int u = (t >= o) ? tmp[t - o] : 0;
        __syncthreads();
        tmp[t] += u;
        __syncthreads();
    }
    bsum[t] = tmp[t] - orig;   // exclusive
}

// ---------------- 2c. per-block scan with base → offsets + cursor ----------
__global__ __launch_bounds__(ST) void k_scanC(
    const int* __restrict__ deg, const int* __restrict__ bsum,
    int* __restrict__ offs, int* __restrict__ cur, int N, int chunk)
{
    int b = blockIdx.x;
    int start = b * chunk, end = min(start + chunk, N);
    __shared__ int tmp[ST];
    __shared__ int carry;
    int t = threadIdx.x;
    if (t == 0) carry = bsum[b];
    __syncthreads();
    for (int i0 = start; i0 < end; i0 += ST) {
        int i = i0 + t;
        int v = (i < end) ? deg[i] : 0;
        tmp[t] = v;
        __syncthreads();
        for (int o = 1; o < ST; o <<= 1) {
            int u = (t >= o) ? tmp[t - o] : 0;
            __syncthreads();
            tmp[t] += u;
            __syncthreads();
        }
        int incl = tmp[t];
        int total = tmp[ST - 1];
        if (i < end) {
            int ex = carry + incl - v;
            offs[i] = ex;
            cur[i] = ex;
        }
        __syncthreads();
        if (t == 0) carry += total;
        __syncthreads();
    }
}

// ---------------- 3. build+scatter messages: mbuf[pos] = relu(x[src]+ea[e])
// Edge-parallel, 16 lanes/edge; ea read SEQUENTIAL; fp16 msg scattered to its
// CSR slot (256B granule, write-side). Proven r12/r15.
__global__ __launch_bounds__(256) void k_msg(
    const short* __restrict__ xb, const float* __restrict__ ea,
    const int* __restrict__ ei, int* __restrict__ cur,
    _Float16* __restrict__ mbuf, int E)
{
    int e = blockIdx.x * 16 + (threadIdx.x >> 4);
    if (e >= E) return;
    int wtid = threadIdx.x & 63;
    int lane = threadIdx.x & 15;
    int c0 = lane * 8;
    int src = ei[e];
    int pos = 0;
    if (lane == 0) {
        int dst = ei[E + e];
        pos = atomicAdd(&cur[dst], 1);
    }
    pos = __shfl(pos, wtid & 48);   // broadcast from group's lane 0

    s16x8 xv = *(const s16x8*)(xb + (size_t)src * D + c0);
    const float* ap = ea + (size_t)e * D + c0;
    f32x4 a0 = __builtin_nontemporal_load((const f32x4*)ap);
    f32x4 a1 = __builtin_nontemporal_load((const f32x4*)(ap + 4));
    f16x8 m;
    #pragma unroll
    for (int i = 0; i < 4; ++i) {
        m[i]     = (_Float16)fmaxf(bf2f(xv[i])     + a0[i], 0.f);
        m[i + 4] = (_Float16)fmaxf(bf2f(xv[i + 4]) + a1[i], 0.f);
    }
    __builtin_nontemporal_store(m, (f16x8*)(mbuf + (size_t)pos * D + c0));
}

// ---------------- 4. aggregate: h[n] = bf16(x[n] + sum msg) ----------------
// Node-parallel, 16 lanes/node; node's messages CONTIGUOUS -> sequential read.
__global__ __launch_bounds__(256) void k_aggr2(
    const short* __restrict__ xb, const _Float16* __restrict__ mbuf,
    const int* __restrict__ offs, const int* __restrict__ deg,
    short* __restrict__ h, int N)
{
    int node = blockIdx.x * 16 + (threadIdx.x >> 4);
    if (node >= N) return;
    int lane = threadIdx.x & 15;
    int c0 = lane * 8;
    int start = offs[node];
    int d = deg[node];
    const _Float16* mp = mbuf + (size_t)start * D + c0;

    float acc[8];
    {
        s16x8 xs = *(const s16x8*)(xb + (size_t)node * D + c0);
        #pragma unroll
        for (int i = 0; i < 8; ++i) acc[i] = bf2f(xs[i]);
    }

    int e = 0;
    for (; e + 4 <= d; e += 4) {
        f16x8 m0 = __builtin_nontemporal_load((const f16x8*)(mp + (size_t)(e + 0) * D));
        f16x8 m1 = __builtin_nontemporal_load((const f16x8*)(mp + (size_t)(e + 1) * D));
        f16x8 m2 = __builtin_nontemporal_load((const f16x8*)(mp + (size_t)(e + 2) * D));
        f16x8 m3 = __builtin_nontemporal_load((const f16x8*)(mp + (size_t)(e + 3) * D));
        #pragma unroll
        for (int i = 0; i < 8; ++i)
            acc[i] += (float)m0[i] + (float)m1[i] + (float)m2[i] + (float)m3[i];
    }
    for (; e < d; ++e) {
        f16x8 m = __builtin_nontemporal_load((const f16x8*)(mp + (size_t)e * D));
        #pragma unroll
        for (int i = 0; i < 8; ++i) acc[i] += (float)m[i];
    }
    s16x8 o;
    #pragma unroll
    for (int i = 0; i < 8; ++i) o[i] = f2bf(acc[i]);
    *(s16x8*)(h + (size_t)node * D + c0) = o;
}

// ---------------- MFMA GEMM: out = [relu](hin_bf16 @ W + bias) -------------
// Operand-swapped (proven r7); NO fused stats (r13/r14 A/B convicted them).
template<int RELU, int OBF>
__global__ __launch_bounds__(256) void k_mgemm(
    const short* __restrict__ hin, const short* __restrict__ wp,
    const float* __restrict__ bias, void* __restrict__ outp, int N)
{
    __shared__ __align__(16) short wB[D * D];   // 32KB packed frags
    int tid = threadIdx.x;
    #pragma unroll
    for (int i = 0; i < 8; ++i) {
        int q = i * 256 + tid;
        *(s16x8*)&wB[q * 8] = *(const s16x8*)&wp[q * 8];
    }
    __syncthreads();

    int wv = tid >> 6, l = tid & 63;
    int cl = l & 15, kg = l >> 4;
    int ntiles = (N + 15) >> 4;

    float4 bv[8];
    #pragma unroll
    for (int c = 0; c < 8; ++c) bv[c] = *(const float4*)&bias[c * 16 + kg * 4];

    for (int tile = blockIdx.x * 4 + wv; tile < ntiles; tile += gridDim.x * 4) {
        int row0 = tile * 16;
        int rowA = min(row0 + cl, N - 1);
        const short* ap = hin + (size_t)rowA * D + kg * 8;
        s16x8 rF[4];
        #pragma unroll
        for (int t = 0; t < 4; ++t)
            rF[t] = *(const s16x8*)(ap + t * 32);

        bool ok = (row0 + cl < N);
        size_t obase = (size_t)(row0 + cl) * D + kg * 4;
        #pragma unroll
        for (int c = 0; c < 8; ++c) {
            f32x4 acc = { bv[c].x, bv[c].y, bv[c].z, bv[c].w };
            #pragma unroll
            for (int t = 0; t < 4; ++t) {
                s16x8 wF = *(const s16x8*)&wB[((t * 8 + c) * 64 + l) * 8];
                acc = __builtin_amdgcn_mfma_f32_16x16x32_bf16(wF, rF[t], acc, 0, 0, 0);
            }
            if (RELU) {
                acc[0] = fmaxf(acc[0], 0.f); acc[1] = fmaxf(acc[1], 0.f);
                acc[2] = fmaxf(acc[2], 0.f); acc[3] = fmaxf(acc[3], 0.f);
            }
            if (ok) {
                if (OBF) {
                    s16x4 o = { f2bf(acc[0]), f2bf(acc[1]), f2bf(acc[2]), f2bf(acc[3]) };
                    *(s16x4*)((short*)outp + obase + c * 16) = o;
                } else {
                    *(float4*)((float*)outp + obase + c * 16) =
                        make_float4(acc[0], acc[1], acc[2], acc[3]);
                }
            }
        }
    }
}

// ---------------- BN batch stats over bf16 h1 ------------------------------
__global__ __launch_bounds__(256) void k_stats(
    const short* __restrict__ h1, float* __restrict__ gsum,
    float* __restrict__ gsq, int N)
{
    __shared__ float ls[D], lq[D];
    int tid = threadIdx.x;
    if (tid < D) { ls[tid] = 0.f; lq[tid] = 0.f; }
    __syncthreads();
    int c0 = (tid & 15) * 8;
    float s[8], q[8];
    #pragma unroll
    for (int i = 0; i < 8; ++i) { s[i] = 0.f; q[i] = 0.f; }
    for (int r = blockIdx.x * 16 + (tid >> 4); r < N; r += gridDim.x * 16) {
        s16x8 v = *(const s16x8*)(h1 + (size_t)r * D + c0);
        #pragma unroll
        for (int i = 0; i < 8; ++i) {
            float f = bf2f(v[i]);
            s[i] += f; q[i] += f * f;
        }
    }
    #pragma unroll
    for (int i = 0; i < 8; ++i) {
        atomicAdd(&ls[c0 + i], s[i]);
        atomicAdd(&lq[c0 + i], q[i]);
    }
    __syncthreads();
    if (tid < D) {
        atomicAdd(&gsum[tid], ls[tid]);
        atomicAdd(&gsq[tid], lq[tid]);
    }
}

// ---------------- fold BN into W2/b2; emit PACKED bf16 W2' + b2' -----------
__global__ __launch_bounds__(128) void k_fold(
    const float* __restrict__ gsum, const float* __restrict__ gsq,
    const float* __restrict__ gamma, const float* __restrict__ beta,
    const float* __restrict__ W2, const float* __restrict__ b2,
    short* __restrict__ wp2, float* __restrict__ b2p, int N)
{
    __shared__ float sS[D], tS[D];
    int j = threadIdx.x;
    float invN = 1.0f / (float)N;
    float mean = gsum[j] * invN;
    float var = gsq[j] * invN - mean * mean;
    float rstd = rsqrtf(var + BN_EPS);
    float s = rstd * gamma[j];
    sS[j] = s;
    tS[j] = beta[j] - mean * s;
    __syncthreads();
    float acc = b2[j];
    #pragma unroll 4
    for (int k = 0; k < D; ++k) {
        float w = W2[k * D + j];
        wp2[wslot(k, j)] = f2bf(sS[k] * w);
        acc = fmaf(tS[k], w, acc);
    }
    b2p[j] = acc;
}

extern "C" void kernel_launch(void* const* d_in, const int* in_sizes, int n_in,
                              void* d_out, int out_size, void* d_ws, size_t ws_size,
                              hipStream_t stream) {
    const float* x     = (const float*)d_in[0];
    const int*   ei    = (const int*)d_in[1];
    const float* ea    = (const float*)d_in[2];
    const float* W1    = (const float*)d_in[3];
    const float* b1    = (const float*)d_in[4];
    const float* gamma = (const float*)d_in[5];
    const float* beta  = (const float*)d_in[6];
    const float* W2    = (const float*)d_in[7];
    const float* b2    = (const float*)d_in[8];
    float* out = (float*)d_out;

    int N = in_sizes[0] / D;
    int E = in_sizes[1] / 2;

    // ---- workspace layout (mbuf first; memset region contiguous deg|gsum|gsq)
    char* ws = (char*)d_ws;
    _Float16* mbuf = (_Float16*)ws;                        // E*D fp16 (409.6 MB)
    int*   deg    = (int*)(ws + (size_t)E * D * sizeof(_Float16)); // N
    float* gsum   = (float*)(deg + N);                     // D
    float* gsq    = gsum + D;                              // D
    float* b2p    = gsq + D;                               // D
    int*   offs   = (int*)(b2p + D);                       // N
    int*   cur    = offs + N;                              // N
    int*   bsum   = cur + N;                               // SB
    short* wp1    = (short*)(bsum + SB);                   // D*D bf16
    short* wp2    = wp1 + D * D;                           // D*D bf16
    short* xb     = wp2 + D * D;                           // N*D bf16 (25.6 MB)
    short* h      = xb + (size_t)N * D;                    // N*D bf16
    short* h1     = h + (size_t)N * D;                     // N*D bf16

    // zero deg + gsum + gsq (contiguous; rest fully overwritten)
    hipMemsetAsync(deg, 0, (size_t)N * sizeof(int) + 2 * D * sizeof(float), stream);

    int chunk = (N + SB - 1) / SB;
    int x8 = (N * D) / 8;
    int prepWork = max(x8, E);

    k_prep<<<(prepWork + 255) / 256, 256, 0, stream>>>(x, xb, ei, deg, W1, wp1, x8, E);
    k_scanA<<<SB, ST, 0, stream>>>(deg, bsum, N, chunk);
    k_scanB<<<1, SB, 0, stream>>>(bsum);
    k_scanC<<<SB, ST, 0, stream>>>(deg, bsum, offs, cur, N, chunk);
    k_msg<<<(E + 15) / 16, 256, 0, stream>>>(xb, ea, ei, cur, mbuf, E);
    k_aggr2<<<(N + 15) / 16, 256, 0, stream>>>(xb, mbuf, offs, deg, h, N);

    int ntiles = (N + 15) / 16;
    int gB = (ntiles + 7) / 8;   // each wave: exactly 2 tiles
    k_mgemm<1, 1><<<gB, 256, 0, stream>>>(h, wp1, b1, h1, N);
    k_stats<<<512, 256, 0, stream>>>(h1, gsum, gsq, N);
    k_fold<<<1, 128, 0, stream>>>(gsum, gsq, gamma, beta, W2, b2, wp2, b2p, N);
    k_mgemm<0, 0><<<gB, 256, 0, stream>>>(h1, wp2, b2p, out, N);
}